// Round 1
// baseline (285.035 us; speedup 1.0000x reference)
//
#include <hip/hip_runtime.h>
#include <hip/hip_bf16.h>
#include <stdint.h>

// Problem constants
#define B_M 512
#define D_K 512
#define C_N 100000
#define S_SCALE 64.0f
#define W_LOSS 0.003f
#define COS_M_C 0.79608379854905604f
#define SIN_M_C 0.60518640573603957f
#define THRESH_C (-0.79608379854905604f)
#define MM_C 0.39337116372842573f

typedef __bf16 bf16x8 __attribute__((ext_vector_type(8)));
typedef float f32x4 __attribute__((ext_vector_type(4)));

typedef const __attribute__((address_space(1))) unsigned char* gptr_t;
typedef __attribute__((address_space(3))) unsigned char* sptr_t;

__device__ __forceinline__ unsigned short f2bf(float f) {
  __bf16 h = (__bf16)f;
  return __builtin_bit_cast(unsigned short, h);
}

// ---------------------------------------------------------------------------
// Kernel 1: normalize emb rows (f32), write swizzled bf16 A-tiles to ws,
// compute target_logit[b] = clip(dot(emb_n[b], kcol)/||kcol||) exactly in f32.
// ---------------------------------------------------------------------------
__global__ __launch_bounds__(256) void prep_kernel(
    const float* __restrict__ emb, const float* __restrict__ Kg,
    const int* __restrict__ label, unsigned char* __restrict__ wsA,
    float* __restrict__ tl)
{
  int b = blockIdx.x, t = threadIdx.x;
  __shared__ float row[512];
  __shared__ float r1[256], r2[256];

  float2 v = ((const float2*)(emb + (size_t)b * 512))[t];
  r1[t] = v.x * v.x + v.y * v.y;
  __syncthreads();
  for (int s = 128; s > 0; s >>= 1) {
    if (t < s) r1[t] += r1[t + s];
    __syncthreads();
  }
  float inv = 1.0f / sqrtf(r1[0]);
  float e0 = v.x * inv, e1 = v.y * inv;
  row[2 * t] = e0;
  row[2 * t + 1] = e1;

  // ws A layout: 8 K-tiles of 64KB, each tile = LDS image [512 rows][128B],
  // byte-in-row XOR-swizzled by ((row&7)<<4). Thread t holds k=2t,2t+1.
  {
    int kk = t >> 5;  // (2t)/64
    int byte_in = (4 * (t & 31)) ^ ((b & 7) << 4);
    ushort2 h;
    h.x = f2bf(e0);
    h.y = f2bf(e1);
    *(ushort2*)(wsA + (size_t)kk * 65536 + b * 128 + byte_in) = h;
  }
  __syncthreads();  // row[] ready; also separates r1 reads from reuse below

  int lab = label[b];
  const float* kc = Kg + lab;
  float dot = 0.f, csq = 0.f;
  for (int d = t; d < 512; d += 256) {
    float kv = kc[(size_t)d * C_N];
    dot += row[d] * kv;
    csq += kv * kv;
  }
  r1[t] = dot;
  r2[t] = csq;
  __syncthreads();
  for (int s = 128; s > 0; s >>= 1) {
    if (t < s) { r1[t] += r1[t + s]; r2[t] += r2[t + s]; }
    __syncthreads();
  }
  if (t == 0) {
    float tlv = r1[0] / sqrtf(r2[0]);
    tl[b] = fminf(1.f, fmaxf(-1.f, tlv));
  }
}

// ---------------------------------------------------------------------------
// Kernel 2: t_new, cos_theta_m[b], final_target_logit[b], center-loss scalar.
// ---------------------------------------------------------------------------
__global__ __launch_bounds__(512) void finalize_kernel(
    const float* __restrict__ tl, const float* __restrict__ t_in,
    float* __restrict__ ctm, float* __restrict__ ftl,
    float* __restrict__ tnew, float* __restrict__ out3)
{
  int t = threadIdx.x;
  float v = tl[t];
  __shared__ float r1[512], r2[512];
  float ac = acosf(v);
  r1[t] = v;
  r2[t] = ac * sqrtf(ac);  // acos^1.5
  __syncthreads();
  for (int s = 256; s > 0; s >>= 1) {
    if (t < s) { r1[t] += r1[t + s]; r2[t] += r2[t + s]; }
    __syncthreads();
  }
  if (t == 0) {
    tnew[0] = 0.99f * t_in[0] + 0.01f * (r1[0] / 512.0f);
    out3[0] = S_SCALE * W_LOSS * (r2[0] / 512.0f);
  }
  float st = sqrtf(fmaxf(0.f, 1.f - v * v));
  float cm = v * COS_M_C - st * SIN_M_C;
  ctm[t] = cm;
  ftl[t] = (v > THRESH_C) ? cm : (v - MM_C);
}

// ---------------------------------------------------------------------------
// Kernel 3: fused GEMM + epilogue.
// BM=512 (full M, kernel read once), BN=64, BK=64, 8 waves (4M x 2N).
// A: global_load_lds from pre-swizzled ws. B: reg-staged f32->bf16 transpose,
// with per-column sumsq accumulated for epilogue 1/||col||.
// ---------------------------------------------------------------------------
#define LDS_BYTES 73728
#define A_BYTES 65536

__global__ __launch_bounds__(512, 4) void gemm_kernel(
    const float* __restrict__ Kg, const unsigned char* __restrict__ wsA,
    const float* __restrict__ ctm_g, const float* __restrict__ ftl_g,
    const int* __restrict__ label, const float* __restrict__ tnew_g,
    float* __restrict__ out1, float* __restrict__ out2)
{
  __shared__ __align__(16) unsigned char smem[LDS_BYTES];
  unsigned char* smemA = smem;
  unsigned char* smemB = smem + A_BYTES;

  int t = threadIdx.x;
  int lane = t & 63, wv = t >> 6;
  int wm = wv >> 1, wn = wv & 1;
  int c0 = blockIdx.x * 64;

  // B staging assignment: thread owns column bn, rows br0..br0+7 per K-step
  int bn = t & 63;
  int br0 = (t >> 6) * 8;
  bool binb = (c0 + bn) < C_N;
  const float* Bg0 = Kg + (size_t)br0 * C_N + c0 + bn;

  f32x4 acc[8][2] = {};
  float csq = 0.f;

  for (int kkt = 0; kkt < 8; ++kkt) {
    __syncthreads();
    // --- stage A: 8x global_load_lds (16B/lane), ws is already the LDS image
    const unsigned char* tA = wsA + (size_t)kkt * 65536;
#pragma unroll
    for (int i = 0; i < 8; ++i) {
      int off = i * 8192 + wv * 1024;
      __builtin_amdgcn_global_load_lds((gptr_t)(tA + off + lane * 16),
                                       (sptr_t)(smemA + off), 16, 0, 0);
    }
    // --- stage B: 8 coalesced f32 loads (one column, 8 rows), cvt, one b128 write
    const float* Bg = Bg0 + (size_t)kkt * 64 * C_N;
    float f[8];
#pragma unroll
    for (int r = 0; r < 8; ++r) f[r] = binb ? Bg[(size_t)r * C_N] : 0.f;
#pragma unroll
    for (int r = 0; r < 8; ++r) csq += f[r] * f[r];
    union { unsigned short u[8]; uint4 q; } pk;
#pragma unroll
    for (int r = 0; r < 8; ++r) pk.u[r] = f2bf(f[r]);
    *(uint4*)(smemB + bn * 128 + ((br0 * 2) ^ ((bn & 7) << 4))) = pk.q;

    __syncthreads();

    // --- compute: 2 K32 sub-steps x (8 m-frags x 2 n-frags)
#pragma unroll
    for (int ks = 0; ks < 2; ++ks) {
      int kbyte = ks * 64 + (lane >> 4) * 16;
      bf16x8 bfr[2];
#pragma unroll
      for (int nf = 0; nf < 2; ++nf) {
        int n = wn * 32 + nf * 16 + (lane & 15);
        bfr[nf] = *(const bf16x8*)(smemB + n * 128 + (kbyte ^ ((n & 7) << 4)));
      }
#pragma unroll
      for (int mf = 0; mf < 8; ++mf) {
        int m = wm * 128 + mf * 16 + (lane & 15);
        bf16x8 afr = *(const bf16x8*)(smemA + m * 128 + (kbyte ^ ((m & 7) << 4)));
        acc[mf][0] = __builtin_amdgcn_mfma_f32_16x16x32_bf16(afr, bfr[0], acc[mf][0], 0, 0, 0);
        acc[mf][1] = __builtin_amdgcn_mfma_f32_16x16x32_bf16(afr, bfr[1], acc[mf][1], 0, 0, 0);
      }
    }
  }

  __syncthreads();
  // --- epilogue scratch aliases the (now dead) A region
  float* colpart = (float*)smem;             // [8][64]
  float* invn    = (float*)(smem + 2048);    // [64]
  float* ctm_s   = (float*)(smem + 4096);    // [512]
  float* ftl_s   = (float*)(smem + 6144);    // [512]
  int*   lab_s   = (int*)(smem + 8192);      // [512]
  ctm_s[t] = ctm_g[t];
  ftl_s[t] = ftl_g[t];
  lab_s[t] = label[t];
  colpart[wv * 64 + bn] = csq;
  __syncthreads();
  if (t < 64) {
    float s = 0.f;
#pragma unroll
    for (int i = 0; i < 8; ++i) s += colpart[i * 64 + t];
    invn[t] = 1.0f / sqrtf(s);
  }
  __syncthreads();

  float tn = tnew_g[0];
  int nbase = wn * 32 + (lane & 15);
  int mbase = wm * 128 + (lane >> 4) * 4;
#pragma unroll
  for (int nf = 0; nf < 2; ++nf) {
    int c = c0 + nbase + nf * 16;
    if (c >= C_N) continue;
    float inv = invn[nbase + nf * 16];
#pragma unroll
    for (int mf = 0; mf < 8; ++mf) {
#pragma unroll
      for (int j = 0; j < 4; ++j) {
        int row = mbase + mf * 16 + j;
        float cosv = fminf(1.f, fmaxf(-1.f, acc[mf][nf][j] * inv));
        size_t idx = (size_t)row * C_N + c;
        out2[idx] = cosv * S_SCALE;  // origin_cos * S
        float ct = (cosv > ctm_s[row]) ? cosv * (tn + cosv) : cosv;
        if (c == lab_s[row]) ct = ftl_s[row];
        out1[idx] = ct * S_SCALE;
      }
    }
  }
}

// ---------------------------------------------------------------------------
extern "C" void kernel_launch(void* const* d_in, const int* in_sizes, int n_in,
                              void* d_out, int out_size, void* d_ws, size_t ws_size,
                              hipStream_t stream)
{
  const float* emb   = (const float*)d_in[0];
  const float* Kg    = (const float*)d_in[1];
  const float* t_in  = (const float*)d_in[2];
  const int*   label = (const int*)d_in[3];

  float* out1 = (float*)d_out;                       // output * S   [512*100000]
  float* out2 = out1 + (size_t)B_M * C_N;            // origin * S   [512*100000]
  float* out3 = out1 + 2 * (size_t)B_M * C_N;        // scalar loss

  unsigned char* wsA = (unsigned char*)d_ws;         // 512KB swizzled bf16 A
  float* tl   = (float*)((unsigned char*)d_ws + 524288);
  float* ctm  = tl + 512;
  float* ftl  = ctm + 512;
  float* tnew = ftl + 512;

  prep_kernel<<<512, 256, 0, stream>>>(emb, Kg, label, wsA, tl);
  finalize_kernel<<<1, 512, 0, stream>>>(tl, t_in, ctm, ftl, tnew, out3);
  int nb = (C_N + 63) / 64;  // 1563
  gemm_kernel<<<nb, 512, 0, stream>>>(Kg, wsA, ctm, ftl, label, tnew, out1, out2);
}

// Round 3
// 169.979 us; speedup vs baseline: 1.6769x; 1.6769x over previous
//
#include <hip/hip_runtime.h>
#include <hip/hip_bf16.h>
#include <stdint.h>

// Problem constants
#define B_M 512
#define D_K 512
#define C_N 100000
#define S_SCALE 64.0f
#define W_LOSS 0.003f
#define COS_M_C 0.79608379854905604f
#define SIN_M_C 0.60518640573603957f
#define THRESH_C (-0.79608379854905604f)
#define MM_C 0.39337116372842573f

typedef __bf16 bf16x8 __attribute__((ext_vector_type(8)));
typedef float f32x4 __attribute__((ext_vector_type(4)));

typedef const __attribute__((address_space(1))) unsigned char* gptr_t;
typedef __attribute__((address_space(3))) unsigned char* sptr_t;

__device__ __forceinline__ unsigned short f2bf(float f) {
  __bf16 h = (__bf16)f;
  return __builtin_bit_cast(unsigned short, h);
}

// ---------------------------------------------------------------------------
// Kernel 1: normalize emb rows (f32), write swizzled bf16 A-tiles to ws,
// compute target_logit[b] exactly in f32.
// wsA layout: 16 tiles (mhalf 0..1  x  ktile 0..7) of 32 KB;
// tile = [256 rows][128 B], byte-in-row XOR ((row&7)<<4)  (LDS image).
// ---------------------------------------------------------------------------
__global__ __launch_bounds__(256) void prep_kernel(
    const float* __restrict__ emb, const float* __restrict__ Kg,
    const int* __restrict__ label, unsigned char* __restrict__ wsA,
    float* __restrict__ tl)
{
  int b = blockIdx.x, t = threadIdx.x;
  __shared__ float row[512];
  __shared__ float r1[256], r2[256];

  float2 v = ((const float2*)(emb + (size_t)b * 512))[t];
  r1[t] = v.x * v.x + v.y * v.y;
  __syncthreads();
  for (int s = 128; s > 0; s >>= 1) {
    if (t < s) r1[t] += r1[t + s];
    __syncthreads();
  }
  float inv = 1.0f / sqrtf(r1[0]);
  float e0 = v.x * inv, e1 = v.y * inv;
  row[2 * t] = e0;
  row[2 * t + 1] = e1;

  {
    int mhalf = b >> 8, lrow = b & 255;
    int kk = t >> 5;  // (2t)/64 : k-tile index
    int byte_in = (4 * (t & 31)) ^ ((lrow & 7) << 4);
    ushort2 h;
    h.x = f2bf(e0);
    h.y = f2bf(e1);
    *(ushort2*)(wsA + (size_t)(mhalf * 8 + kk) * 32768 + lrow * 128 + byte_in) = h;
  }
  __syncthreads();

  int lab = label[b];
  const float* kc = Kg + lab;
  float dot = 0.f, csq = 0.f;
  for (int d = t; d < 512; d += 256) {
    float kv = kc[(size_t)d * C_N];
    dot += row[d] * kv;
    csq += kv * kv;
  }
  r1[t] = dot;
  r2[t] = csq;
  __syncthreads();
  for (int s = 128; s > 0; s >>= 1) {
    if (t < s) { r1[t] += r1[t + s]; r2[t] += r2[t + s]; }
    __syncthreads();
  }
  if (t == 0) {
    float tlv = r1[0] / sqrtf(r2[0]);
    tl[b] = fminf(1.f, fmaxf(-1.f, tlv));
  }
}

// ---------------------------------------------------------------------------
// Kernel 2: t_new, cos_theta_m[b], final_target_logit[b], center-loss scalar.
// ---------------------------------------------------------------------------
__global__ __launch_bounds__(512) void finalize_kernel(
    const float* __restrict__ tl, const float* __restrict__ t_in,
    float* __restrict__ ctm, float* __restrict__ ftl,
    float* __restrict__ tnew, float* __restrict__ out3)
{
  int t = threadIdx.x;
  float v = tl[t];
  __shared__ float r1[512], r2[512];
  float ac = acosf(v);
  r1[t] = v;
  r2[t] = ac * sqrtf(ac);  // acos^1.5
  __syncthreads();
  for (int s = 256; s > 0; s >>= 1) {
    if (t < s) { r1[t] += r1[t + s]; r2[t] += r2[t + s]; }
    __syncthreads();
  }
  if (t == 0) {
    tnew[0] = 0.99f * t_in[0] + 0.01f * (r1[0] / 512.0f);
    out3[0] = S_SCALE * W_LOSS * (r2[0] / 512.0f);
  }
  float st = sqrtf(fmaxf(0.f, 1.f - v * v));
  float cm = v * COS_M_C - st * SIN_M_C;
  ctm[t] = cm;
  ftl[t] = (v > THRESH_C) ? cm : (v - MM_C);
}

// ---------------------------------------------------------------------------
// Kernel 3: fused GEMM + epilogue.
// BM=256, BN=128, BK=64. 512 threads, 8 waves (2M x 4N), per-wave 128x32.
// A double-buffered (2x32KB) via global_load_lds issued AFTER barrier-1 so
// the DMA overlaps MFMA; explicit s_waitcnt vmcnt(0) before barrier-2 pins
// it (race-safe). B single buffer (16KB): ds_write sits between the two
// barriers (write-after-read and read-after-write both barrier-separated).
// Epilogue: acc -> LDS (f32, XOR-swizzled) -> 512B-contiguous dwordx4 stores.
// ---------------------------------------------------------------------------
#define LDS_TOTAL 81920  // A dbuf: 2*32768 @ [0,65536); B: 16384 @ [65536,81920)

__global__ __launch_bounds__(512, 2) void gemm_kernel(
    const float* __restrict__ Kg, const unsigned char* __restrict__ wsA,
    const float* __restrict__ ctm_g, const float* __restrict__ ftl_g,
    const int* __restrict__ label, const float* __restrict__ tnew_g,
    float* __restrict__ out1, float* __restrict__ out2)
{
  __shared__ __align__(16) unsigned char smem[LDS_TOTAL];

  int t = threadIdx.x;
  int lane = t & 63, wv = t >> 6;
  int wm = wv >> 2, wn = wv & 3;  // 2M x 4N

  // m204 bijective XCD swizzle: nwg=1564, q=195, r=4. Contiguous swz ids per
  // XCD -> the two mhalf-blocks of one pid share an L2 (Kg panel reuse).
  int bid = blockIdx.x;
  {
    const int q8 = 1564 / 8, r8 = 1564 % 8;
    int xcd = bid & 7, seq = bid >> 3;
    bid = (xcd < r8 ? xcd * (q8 + 1) : r8 * (q8 + 1) + (xcd - r8) * q8) + seq;
  }
  int pid = bid >> 1, mhalf = bid & 1;
  long c0 = (long)pid * 128;

  // B staging: thread owns column c (t&127), k-segment kseg (t>>7): 16 k's
  int c = t & 127, kseg = t >> 7;
  bool binb = (c0 + c) < C_N;
  const float* Bcol = Kg + c0 + c;

  f32x4 acc[8][2] = {};
  float csq = 0.f;
  float bf[16];

  const unsigned char* wsTile = wsA + (size_t)mhalf * (8 * 32768);
  unsigned char* smemB = smem + 65536;

  // ---- prologue: stage step 0 (A -> buf0, B -> B-buf)
  {
#pragma unroll
    for (int i = 0; i < 4; ++i) {
      int off = wv * 4096 + i * 1024;
      __builtin_amdgcn_global_load_lds((gptr_t)(wsTile + off + lane * 16),
                                       (sptr_t)(smem + off), 16, 0, 0);
    }
#pragma unroll
    for (int i = 0; i < 16; ++i) bf[i] = binb ? Bcol[(size_t)(kseg * 16 + i) * C_N] : 0.f;
#pragma unroll
    for (int i = 0; i < 16; ++i) csq += bf[i] * bf[i];
    union { unsigned short u[16]; uint4 q[2]; } pk;
#pragma unroll
    for (int i = 0; i < 16; ++i) pk.u[i] = f2bf(bf[i]);
    unsigned char* brow = smemB + c * 128;
#pragma unroll
    for (int h = 0; h < 2; ++h)
      *(uint4*)(brow + ((kseg * 32 + h * 16) ^ ((c & 7) << 4))) = pk.q[h];
    asm volatile("s_waitcnt vmcnt(0)" ::: "memory");
    __builtin_amdgcn_sched_barrier(0);
    __syncthreads();
  }

  // ---- main loop: 8 K-steps, A dbuf, 2 barriers/step, explicit DMA drain
  for (int kkt = 0; kkt < 8; ++kkt) {
    int cur = kkt & 1;
    if (kkt < 7) {
      // prefetch A[kkt+1] into the other buffer (DMA overlaps compute below)
      const unsigned char* tA = wsTile + (size_t)(kkt + 1) * 32768;
#pragma unroll
      for (int i = 0; i < 4; ++i) {
        int off = wv * 4096 + i * 1024;
        __builtin_amdgcn_global_load_lds((gptr_t)(tA + off + lane * 16),
                                         (sptr_t)(smem + (cur ^ 1) * 32768 + off), 16, 0, 0);
      }
      int kbase = (kkt + 1) * 64 + kseg * 16;
#pragma unroll
      for (int i = 0; i < 16; ++i) bf[i] = binb ? Bcol[(size_t)(kbase + i) * C_N] : 0.f;
    }

    // compute current buffers
    const unsigned char* Ab = smem + cur * 32768;
#pragma unroll
    for (int ks = 0; ks < 2; ++ks) {
      int kb = ks * 64 + (lane >> 4) * 16;
      bf16x8 bfr[2];
#pragma unroll
      for (int nf = 0; nf < 2; ++nf) {
        int n = wn * 32 + nf * 16 + (lane & 15);
        bfr[nf] = *(const bf16x8*)(smemB + n * 128 + (kb ^ ((n & 7) << 4)));
      }
#pragma unroll
      for (int mf = 0; mf < 8; ++mf) {
        int m = wm * 128 + mf * 16 + (lane & 15);
        bf16x8 afr = *(const bf16x8*)(Ab + m * 128 + (kb ^ ((m & 7) << 4)));
        acc[mf][0] = __builtin_amdgcn_mfma_f32_16x16x32_bf16(afr, bfr[0], acc[mf][0], 0, 0, 0);
        acc[mf][1] = __builtin_amdgcn_mfma_f32_16x16x32_bf16(afr, bfr[1], acc[mf][1], 0, 0, 0);
      }
    }

    // pin the A-DMA (and bf loads) before anyone can cross the barrier
    asm volatile("s_waitcnt vmcnt(0)" ::: "memory");
    __builtin_amdgcn_sched_barrier(0);
    __syncthreads();  // everyone done reading B-buf; A[kkt+1] landed

    if (kkt < 7) {
#pragma unroll
      for (int i = 0; i < 16; ++i) csq += bf[i] * bf[i];
      union { unsigned short u[16]; uint4 q[2]; } pk;
#pragma unroll
      for (int i = 0; i < 16; ++i) pk.u[i] = f2bf(bf[i]);
      unsigned char* brow = smemB + c * 128;
#pragma unroll
      for (int h = 0; h < 2; ++h)
        *(uint4*)(brow + ((kseg * 32 + h * 16) ^ ((c & 7) << 4))) = pk.q[h];
    }
    __syncthreads();  // B[kkt+1] visible
  }

  // ---- column norms + per-row params (alias B region; all buffers dead)
  float* colpart = (float*)(smemB);         // [512]
  float* invn    = (float*)(smemB + 2048);  // [128]
  float* ctm_s   = (float*)(smemB + 2560);  // [256]
  float* ftl_s   = (float*)(smemB + 3584);  // [256]
  int*   lab_s   = (int*)  (smemB + 4608);  // [256]
  colpart[t] = csq;
  if (t < 256) {
    ctm_s[t] = ctm_g[mhalf * 256 + t];
    ftl_s[t] = ftl_g[mhalf * 256 + t];
    lab_s[t] = label[mhalf * 256 + t];
  }
  __syncthreads();
  if (t < 128) {
    float s = colpart[t] + colpart[128 + t] + colpart[256 + t] + colpart[384 + t];
    invn[t] = 1.0f / sqrtf(fmaxf(s, 1e-30f));
  }
  __syncthreads();
  float tn = tnew_g[0];

  // ---- epilogue: 2 chunks of 128 rows; stage acc in LDS, stream 512B rows
  for (int q = 0; q < 2; ++q) {
    if (wm == q) {
#pragma unroll
      for (int mf = 0; mf < 8; ++mf) {
#pragma unroll
        for (int nf = 0; nf < 2; ++nf) {
#pragma unroll
          for (int j = 0; j < 4; ++j) {
            int row = mf * 16 + (lane >> 4) * 4 + j;
            int col = wn * 32 + nf * 16 + (lane & 15);
            *(float*)(smem + row * 512 + ((col * 4) ^ (((row >> 2) & 3) << 6))) =
                acc[mf][nf][j];
          }
        }
      }
    }
    __syncthreads();
#pragma unroll
    for (int rr = 0; rr < 8; ++rr) {
      int row = rr * 16 + (t >> 5);
      int cb = (t & 31) * 4;
      f32x4 v = *(const f32x4*)(smem + row * 512 + ((cb * 4) ^ (((row >> 2) & 3) << 6)));
      long cgs = c0 + cb;
      if (cgs < C_N) {
        int lrow = q * 128 + row;
        float cm = ctm_s[lrow], fl = ftl_s[lrow];
        int lb = lab_s[lrow];
        f32x4 iv = *(const f32x4*)(invn + cb);
        f32x4 o1v, o2v;
#pragma unroll
        for (int jj = 0; jj < 4; ++jj) {
          float cosv = fminf(1.f, fmaxf(-1.f, v[jj] * iv[jj]));
          o2v[jj] = cosv * S_SCALE;
          float ct = (cosv > cm) ? cosv * (tn + cosv) : cosv;
          if (lb == (int)(cgs + jj)) ct = fl;
          o1v[jj] = ct * S_SCALE;
        }
        size_t idx = (size_t)(mhalf * 256 + lrow) * C_N + cgs;
        *(f32x4*)(out1 + idx) = o1v;
        *(f32x4*)(out2 + idx) = o2v;
      }
    }
    __syncthreads();
  }
}

// ---------------------------------------------------------------------------
extern "C" void kernel_launch(void* const* d_in, const int* in_sizes, int n_in,
                              void* d_out, int out_size, void* d_ws, size_t ws_size,
                              hipStream_t stream)
{
  const float* emb   = (const float*)d_in[0];
  const float* Kg    = (const float*)d_in[1];
  const float* t_in  = (const float*)d_in[2];
  const int*   label = (const int*)d_in[3];

  float* out1 = (float*)d_out;                 // output * S   [512*100000]
  float* out2 = out1 + (size_t)B_M * C_N;      // origin * S   [512*100000]
  float* out3 = out1 + 2 * (size_t)B_M * C_N;  // scalar loss

  unsigned char* wsA = (unsigned char*)d_ws;   // 512KB swizzled bf16 A tiles
  float* tl   = (float*)((unsigned char*)d_ws + 524288);
  float* ctm  = tl + 512;
  float* ftl  = ctm + 512;
  float* tnew = ftl + 512;

  prep_kernel<<<512, 256, 0, stream>>>(emb, Kg, label, wsA, tl);
  finalize_kernel<<<1, 512, 0, stream>>>(tl, t_in, ctm, ftl, tnew, out3);
  int nb = 2 * ((C_N + 127) / 128);  // 2 * 782 = 1564
  gemm_kernel<<<nb, 512, 0, stream>>>(Kg, wsA, ctm, ftl, label, tnew, out1, out2);
}

// Round 4
// 159.245 us; speedup vs baseline: 1.7899x; 1.0674x over previous
//
#include <hip/hip_runtime.h>
#include <hip/hip_bf16.h>
#include <stdint.h>

// Problem constants
#define B_M 512
#define D_K 512
#define C_N 100000
#define S_SCALE 64.0f
#define W_LOSS 0.003f
#define COS_M_C 0.79608379854905604f
#define SIN_M_C 0.60518640573603957f
#define THRESH_C (-0.79608379854905604f)
#define MM_C 0.39337116372842573f

typedef __bf16 bf16x8 __attribute__((ext_vector_type(8)));
typedef float f32x4 __attribute__((ext_vector_type(4)));

typedef const __attribute__((address_space(1))) unsigned char* gptr_t;
typedef __attribute__((address_space(3))) unsigned char* sptr_t;

__device__ __forceinline__ unsigned short f2bf(float f) {
  __bf16 h = (__bf16)f;
  return __builtin_bit_cast(unsigned short, h);
}

// ---------------------------------------------------------------------------
// Kernel 1: normalize emb rows (f32), write swizzled bf16 A-tiles to ws,
// compute target_logit[b] exactly in f32.
// wsA layout: 16 tiles (mhalf 0..1  x  ktile 0..7) of 32 KB;
// tile = [256 rows][128 B], byte-in-row XOR ((row&7)<<4)  (LDS image).
// ---------------------------------------------------------------------------
__global__ __launch_bounds__(256) void prep_kernel(
    const float* __restrict__ emb, const float* __restrict__ Kg,
    const int* __restrict__ label, unsigned char* __restrict__ wsA,
    float* __restrict__ tl)
{
  int b = blockIdx.x, t = threadIdx.x;
  __shared__ float row[512];
  __shared__ float r1[256], r2[256];

  float2 v = ((const float2*)(emb + (size_t)b * 512))[t];
  r1[t] = v.x * v.x + v.y * v.y;
  __syncthreads();
  for (int s = 128; s > 0; s >>= 1) {
    if (t < s) r1[t] += r1[t + s];
    __syncthreads();
  }
  float inv = 1.0f / sqrtf(r1[0]);
  float e0 = v.x * inv, e1 = v.y * inv;
  row[2 * t] = e0;
  row[2 * t + 1] = e1;

  {
    int mhalf = b >> 8, lrow = b & 255;
    int kk = t >> 5;  // (2t)/64 : k-tile index
    int byte_in = (4 * (t & 31)) ^ ((lrow & 7) << 4);
    ushort2 h;
    h.x = f2bf(e0);
    h.y = f2bf(e1);
    *(ushort2*)(wsA + (size_t)(mhalf * 8 + kk) * 32768 + lrow * 128 + byte_in) = h;
  }
  __syncthreads();

  int lab = label[b];
  const float* kc = Kg + lab;
  float dot = 0.f, csq = 0.f;
  for (int d = t; d < 512; d += 256) {
    float kv = kc[(size_t)d * C_N];
    dot += row[d] * kv;
    csq += kv * kv;
  }
  r1[t] = dot;
  r2[t] = csq;
  __syncthreads();
  for (int s = 128; s > 0; s >>= 1) {
    if (t < s) { r1[t] += r1[t + s]; r2[t] += r2[t + s]; }
    __syncthreads();
  }
  if (t == 0) {
    float tlv = r1[0] / sqrtf(r2[0]);
    tl[b] = fminf(1.f, fmaxf(-1.f, tlv));
  }
}

// ---------------------------------------------------------------------------
// Kernel 2: t_new, cos_theta_m[b], final_target_logit[b], center-loss scalar.
// ---------------------------------------------------------------------------
__global__ __launch_bounds__(512) void finalize_kernel(
    const float* __restrict__ tl, const float* __restrict__ t_in,
    float* __restrict__ ctm, float* __restrict__ ftl,
    float* __restrict__ tnew, float* __restrict__ out3)
{
  int t = threadIdx.x;
  float v = tl[t];
  __shared__ float r1[512], r2[512];
  float ac = acosf(v);
  r1[t] = v;
  r2[t] = ac * sqrtf(ac);  // acos^1.5
  __syncthreads();
  for (int s = 256; s > 0; s >>= 1) {
    if (t < s) { r1[t] += r1[t + s]; r2[t] += r2[t + s]; }
    __syncthreads();
  }
  if (t == 0) {
    tnew[0] = 0.99f * t_in[0] + 0.01f * (r1[0] / 512.0f);
    out3[0] = S_SCALE * W_LOSS * (r2[0] / 512.0f);
  }
  float st = sqrtf(fmaxf(0.f, 1.f - v * v));
  float cm = v * COS_M_C - st * SIN_M_C;
  ctm[t] = cm;
  ftl[t] = (v > THRESH_C) ? cm : (v - MM_C);
}

// ---------------------------------------------------------------------------
// Kernel 3: fused GEMM + epilogue.
// BM=256, BN=128, BK=64. 512 threads, 8 waves (2M x 4N), per-wave 128x32.
// Pipeline: A dbuf in LDS (gll prefetch 1 ahead), B prefetch 2 ahead into
// two register sets, single B LDS buffer. Counted s_waitcnt vmcnt(16)
// before barrier-1 retires exactly {B[k+1] regs, A[k+1] DMA} and leaves
// B[k+2] (16 loads) in flight across the barriers. 2 barriers/step.
// Epilogue: acc -> LDS (f32, XOR-swizzled) -> 512B-contiguous NT stores.
// ---------------------------------------------------------------------------
#define LDS_TOTAL 81920  // A dbuf: 2*32768 @ [0,65536); B: 16384 @ [65536,81920)

__global__ __launch_bounds__(512, 2) void gemm_kernel(
    const float* __restrict__ Kg, const unsigned char* __restrict__ wsA,
    const float* __restrict__ ctm_g, const float* __restrict__ ftl_g,
    const int* __restrict__ label, const float* __restrict__ tnew_g,
    float* __restrict__ out1, float* __restrict__ out2)
{
  __shared__ __align__(16) unsigned char smem[LDS_TOTAL];

  int t = threadIdx.x;
  int lane = t & 63, wv = t >> 6;
  int wm = wv >> 2, wn = wv & 3;  // 2M x 4N

  // m204 bijective XCD swizzle: nwg=1564, q=195, r=4. Contiguous swz ids per
  // XCD -> the two mhalf-blocks of one pid share an L2 (Kg panel reuse).
  int bid = blockIdx.x;
  {
    const int q8 = 1564 / 8, r8 = 1564 % 8;
    int xcd = bid & 7, seq = bid >> 3;
    bid = (xcd < r8 ? xcd * (q8 + 1) : r8 * (q8 + 1) + (xcd - r8) * q8) + seq;
  }
  int pid = bid >> 1, mhalf = bid & 1;
  long c0 = (long)pid * 128;

  // B staging: thread owns column c (t&127), k-segment kseg (t>>7): 16 k's
  int c = t & 127, kseg = t >> 7;
  bool binb = (c0 + c) < C_N;
  const float* Bcol = Kg + c0 + c + (size_t)kseg * 16 * C_N;

  f32x4 acc[8][2] = {};
  float csq = 0.f;
  float bf0[16], bf1[16];  // B[j] lives in set (j&1)

  const unsigned char* wsTile = wsA + (size_t)mhalf * (8 * 32768);
  unsigned char* smemB = smem + 65536;
  unsigned char* browB = smemB + c * 128;

#define LOAD_B(dst, j)                                                       \
  {                                                                          \
    const float* src = Bcol + (size_t)((j) * 64) * C_N;                      \
    _Pragma("unroll") for (int i = 0; i < 16; ++i)                           \
        dst[i] = binb ? src[(size_t)i * C_N] : 0.f;                          \
  }

#define WRITE_B(src)                                                         \
  {                                                                          \
    _Pragma("unroll") for (int i = 0; i < 16; ++i) csq += src[i] * src[i];   \
    union { unsigned short u[16]; uint4 q[2]; } pk;                          \
    _Pragma("unroll") for (int i = 0; i < 16; ++i) pk.u[i] = f2bf(src[i]);   \
    _Pragma("unroll") for (int h = 0; h < 2; ++h)                            \
      *(uint4*)(browB + ((kseg * 32 + h * 16) ^ ((c & 7) << 4))) = pk.q[h];  \
  }

  // ---- prologue: A[0] DMA, B[0]/B[1] reg loads, B[0] -> LDS
  {
#pragma unroll
    for (int i = 0; i < 4; ++i) {
      int off = wv * 4096 + i * 1024;
      __builtin_amdgcn_global_load_lds((gptr_t)(wsTile + off + lane * 16),
                                       (sptr_t)(smem + off), 16, 0, 0);
    }
    __builtin_amdgcn_sched_barrier(0);
    LOAD_B(bf0, 0);
    __builtin_amdgcn_sched_barrier(0);
    LOAD_B(bf1, 1);
    __builtin_amdgcn_sched_barrier(0);
    asm volatile("s_waitcnt vmcnt(16)" ::: "memory");  // A[0]+B[0] done
    __builtin_amdgcn_sched_barrier(0);
    WRITE_B(bf0);
    __syncthreads();
  }

  // ---- main loop: 8 K-steps, fully unrolled (static reg-set selects)
#pragma unroll
  for (int kkt = 0; kkt < 8; ++kkt) {
    int cur = kkt & 1;
    if (kkt < 7) {
      const unsigned char* tA = wsTile + (size_t)(kkt + 1) * 32768;
#pragma unroll
      for (int i = 0; i < 4; ++i) {
        int off = wv * 4096 + i * 1024;
        __builtin_amdgcn_global_load_lds((gptr_t)(tA + off + lane * 16),
                                         (sptr_t)(smem + (cur ^ 1) * 32768 + off), 16, 0, 0);
      }
      __builtin_amdgcn_sched_barrier(0);
    }
    if (kkt < 6) {
      if (kkt & 1) { LOAD_B(bf1, kkt + 2); } else { LOAD_B(bf0, kkt + 2); }
      __builtin_amdgcn_sched_barrier(0);
    }

    // compute current buffers
    const unsigned char* Ab = smem + cur * 32768;
#pragma unroll
    for (int ks = 0; ks < 2; ++ks) {
      int kb = ks * 64 + (lane >> 4) * 16;
      bf16x8 bfr[2];
#pragma unroll
      for (int nf = 0; nf < 2; ++nf) {
        int n = wn * 32 + nf * 16 + (lane & 15);
        bfr[nf] = *(const bf16x8*)(smemB + n * 128 + (kb ^ ((n & 7) << 4)));
      }
#pragma unroll
      for (int mf = 0; mf < 8; ++mf) {
        int m = wm * 128 + mf * 16 + (lane & 15);
        bf16x8 afr = *(const bf16x8*)(Ab + m * 128 + (kb ^ ((m & 7) << 4)));
        acc[mf][0] = __builtin_amdgcn_mfma_f32_16x16x32_bf16(afr, bfr[0], acc[mf][0], 0, 0, 0);
        acc[mf][1] = __builtin_amdgcn_mfma_f32_16x16x32_bf16(afr, bfr[1], acc[mf][1], 0, 0, 0);
      }
    }

    // counted wait: retire {B[k+1] regs (16) , A[k+1] DMA (4)}, keep B[k+2]
    // (16 newest) in flight across the barrier. Last steps drain fully.
    if (kkt < 6) {
      asm volatile("s_waitcnt vmcnt(16)" ::: "memory");
    } else {
      asm volatile("s_waitcnt vmcnt(0)" ::: "memory");
    }
    __builtin_amdgcn_sched_barrier(0);
    __syncthreads();  // barrier-1: B-LDS reads done, A[k+1] landed

    if (kkt < 7) {
      if (kkt & 1) { WRITE_B(bf0); } else { WRITE_B(bf1); }
      __syncthreads();  // barrier-2: B[k+1] visible
    }
  }

  // ---- column norms + per-row params (alias B region; all buffers dead)
  float* colpart = (float*)(smemB);         // [512]
  float* invn    = (float*)(smemB + 2048);  // [128]
  float* ctm_s   = (float*)(smemB + 2560);  // [256]
  float* ftl_s   = (float*)(smemB + 3584);  // [256]
  int*   lab_s   = (int*)  (smemB + 4608);  // [256]
  colpart[t] = csq;
  if (t < 256) {
    ctm_s[t] = ctm_g[mhalf * 256 + t];
    ftl_s[t] = ftl_g[mhalf * 256 + t];
    lab_s[t] = label[mhalf * 256 + t];
  }
  __syncthreads();
  if (t < 128) {
    float s = colpart[t] + colpart[128 + t] + colpart[256 + t] + colpart[384 + t];
    invn[t] = 1.0f / sqrtf(fmaxf(s, 1e-30f));
  }
  __syncthreads();
  float tn = tnew_g[0];

  // ---- epilogue: 2 chunks of 128 rows; stage acc in LDS, stream 512B rows
  for (int q = 0; q < 2; ++q) {
    if (wm == q) {
#pragma unroll
      for (int mf = 0; mf < 8; ++mf) {
#pragma unroll
        for (int nf = 0; nf < 2; ++nf) {
#pragma unroll
          for (int j = 0; j < 4; ++j) {
            int row = mf * 16 + (lane >> 4) * 4 + j;
            int col = wn * 32 + nf * 16 + (lane & 15);
            *(float*)(smem + row * 512 + ((col * 4) ^ (((row >> 2) & 3) << 6))) =
                acc[mf][nf][j];
          }
        }
      }
    }
    __syncthreads();
#pragma unroll
    for (int rr = 0; rr < 8; ++rr) {
      int row = rr * 16 + (t >> 5);
      int cb = (t & 31) * 4;
      f32x4 v = *(const f32x4*)(smem + row * 512 + ((cb * 4) ^ (((row >> 2) & 3) << 6)));
      long cgs = c0 + cb;
      if (cgs < C_N) {
        int lrow = q * 128 + row;
        float cm = ctm_s[lrow], fl = ftl_s[lrow];
        int lb = lab_s[lrow];
        f32x4 iv = *(const f32x4*)(invn + cb);
        f32x4 o1v, o2v;
#pragma unroll
        for (int jj = 0; jj < 4; ++jj) {
          float cosv = fminf(1.f, fmaxf(-1.f, v[jj] * iv[jj]));
          o2v[jj] = cosv * S_SCALE;
          float ct = (cosv > cm) ? cosv * (tn + cosv) : cosv;
          if (lb == (int)(cgs + jj)) ct = fl;
          o1v[jj] = ct * S_SCALE;
        }
        size_t idx = (size_t)(mhalf * 256 + lrow) * C_N + cgs;
        __builtin_nontemporal_store(o1v, (f32x4*)(out1 + idx));
        __builtin_nontemporal_store(o2v, (f32x4*)(out2 + idx));
      }
    }
    __syncthreads();
  }
#undef LOAD_B
#undef WRITE_B
}

// ---------------------------------------------------------------------------
extern "C" void kernel_launch(void* const* d_in, const int* in_sizes, int n_in,
                              void* d_out, int out_size, void* d_ws, size_t ws_size,
                              hipStream_t stream)
{
  const float* emb   = (const float*)d_in[0];
  const float* Kg    = (const float*)d_in[1];
  const float* t_in  = (const float*)d_in[2];
  const int*   label = (const int*)d_in[3];

  float* out1 = (float*)d_out;                 // output * S   [512*100000]
  float* out2 = out1 + (size_t)B_M * C_N;      // origin * S   [512*100000]
  float* out3 = out1 + 2 * (size_t)B_M * C_N;  // scalar loss

  unsigned char* wsA = (unsigned char*)d_ws;   // 512KB swizzled bf16 A tiles
  float* tl   = (float*)((unsigned char*)d_ws + 524288);
  float* ctm  = tl + 512;
  float* ftl  = ctm + 512;
  float* tnew = ftl + 512;

  prep_kernel<<<512, 256, 0, stream>>>(emb, Kg, label, wsA, tl);
  finalize_kernel<<<1, 512, 0, stream>>>(tl, t_in, ctm, ftl, tnew, out3);
  int nb = 2 * ((C_N + 127) / 128);  // 2 * 782 = 1564
  gemm_kernel<<<nb, 512, 0, stream>>>(Kg, wsA, ctm, ftl, label, tnew, out1, out2);
}